// Round 1
// baseline (1532.071 us; speedup 1.0000x reference)
//
#include <hip/hip_runtime.h>
#include <stdint.h>
#include <stddef.h>

// AttentionGRUCell on MI355X (gfx950).  B=16384, EMB=1024, HID=1024, COMB=2048.
// All GEMMs bf16 MFMA 16x16x32.  This version ports the fused GEMM to the
// 256x256-tile 8-phase schedule (learn_hip m201 template): BK=64, 512 threads
// (8 waves, 2Mx4N), 128 KiB double-buffered LDS, one half-tile (16 KB) staged
// per phase via global_load_lds dwordx4, counted s_waitcnt vmcnt(6) only at
// phases 4/8 (3 half-tiles always in flight), raw s_barrier pairs around each
// 16-MFMA quadrant cluster, s_setprio(1) around MFMA.  LDS keeps the
// baseline's measured-zero-conflict XOR swizzle (kgroup ^= row&7, source-side
// pre-swizzle + read-side swizzle).
//
// Memory choreography (cross-launch ordering makes input buffers reusable):
//   cvt_xh : x,h f32 -> x_bf (ws), h_bf (d_out t-region, dead until T)
//   cvt_a  : a f32   -> a_bf (x's input buffer, x f32 now dead)
//   transpose_all: 12 weights f32 [K,N] -> bf16 [N,K] in ws
//   R: rh = sigmoid(xWr+hUr+aCr)*h -> h-buffer[0:32M)      (h f32 dead)
//   Z: z  = sigmoid(xWz+hUz+aCz)   -> h-buffer[32M:64M)
//   S: s  = (1-z)h + z*tanh(xW+rhU+aC) -> d_out[0:64MB) f32, s_bf -> a-buffer
//   T: t  = relu(xVo+sUo+aCo)      -> d_out[64MB:128MB) f32 (over dead h_bf)

#define MODE_Z 0
#define MODE_R 1
#define MODE_S 2
#define MODE_T 3

typedef __attribute__((ext_vector_type(8))) __bf16 bf16x8;
typedef __attribute__((ext_vector_type(4))) float f32x4;
typedef __attribute__((ext_vector_type(8))) unsigned short us8;

__device__ __forceinline__ unsigned short f2bf(float f) {
  union { float f; unsigned u; } v; v.f = f;
  unsigned r = 0x7FFFu + ((v.u >> 16) & 1u);   // round-to-nearest-even
  return (unsigned short)((v.u + r) >> 16);
}
__device__ __forceinline__ float bf2f(unsigned short h) {
  union { unsigned u; float f; } v; v.u = ((unsigned)h) << 16;
  return v.f;
}

__device__ __forceinline__ void gload_lds16(const unsigned short* g, unsigned short* l) {
  __builtin_amdgcn_global_load_lds(
      (const __attribute__((address_space(1))) void*)g,
      (__attribute__((address_space(3))) void*)l, 16, 0, 0);
}

// ---- f32 -> bf16 converters (8 elems/thread, fully coalesced) ----
__global__ void cvt_xh(const float* __restrict__ x, const float* __restrict__ h,
                       unsigned short* __restrict__ xb, unsigned short* __restrict__ hb) {
  const size_t NX = 16777216;  // 16384*1024
  size_t i = ((size_t)blockIdx.x * 256 + threadIdx.x) * 8;
  const float* s; unsigned short* d; size_t off;
  if (i < NX) { s = x; d = xb; off = i; } else { s = h; d = hb; off = i - NX; }
  f32x4 v0 = *(const f32x4*)(s + off);
  f32x4 v1 = *(const f32x4*)(s + off + 4);
  us8 p = { f2bf(v0.x), f2bf(v0.y), f2bf(v0.z), f2bf(v0.w),
            f2bf(v1.x), f2bf(v1.y), f2bf(v1.z), f2bf(v1.w) };
  *(us8*)(d + off) = p;
}

__global__ void cvt_a(const float* __restrict__ a, unsigned short* __restrict__ ab) {
  size_t i = ((size_t)blockIdx.x * 256 + threadIdx.x) * 8;
  f32x4 v0 = *(const f32x4*)(a + i);
  f32x4 v1 = *(const f32x4*)(a + i + 4);
  us8 p = { f2bf(v0.x), f2bf(v0.y), f2bf(v0.z), f2bf(v0.w),
            f2bf(v1.x), f2bf(v1.y), f2bf(v1.z), f2bf(v1.w) };
  *(us8*)(ab + i) = p;
}

// ---- batched weight transpose: f32 [K,1024] -> bf16 [1024,K] ----
struct TArgs {
  const float* src[12];
  unsigned short* dst[12];
};

__global__ void transpose_all(TArgs ta) {
  __shared__ float tile[32][33];
  int t = blockIdx.x;
  int w, K, local;
  if (t < 8192) { w = t >> 10; K = 1024; local = t & 1023; }
  else { int t2 = t - 8192; w = 8 + (t2 >> 11); K = 2048; local = t2 & 2047; }
  int kb = (K == 1024) ? ((local & 31) << 5) : ((local & 63) << 5);
  int nb = (K == 1024) ? ((local >> 5) << 5) : ((local >> 6) << 5);
  const float* src = ta.src[w];
  unsigned short* dst = ta.dst[w];
  int tx = threadIdx.x, ty = threadIdx.y;   // block 32x8
  #pragma unroll
  for (int i = 0; i < 32; i += 8)
    tile[ty + i][tx] = src[(size_t)(kb + ty + i) * 1024 + nb + tx];
  __syncthreads();
  #pragma unroll
  for (int i = 0; i < 32; i += 8)
    dst[(size_t)(nb + ty + i) * K + kb + tx] = f2bf(tile[tx][ty + i]);
}

#define BARRIER() asm volatile("s_barrier" ::: "memory")
#define WAIT_VM(N) asm volatile("s_waitcnt vmcnt(" #N ")" ::: "memory")
#define PRIO1() __builtin_amdgcn_s_setprio(1)
#define PRIO0() __builtin_amdgcn_s_setprio(0)

// ---- fused GEMM: 256x256 tile, 8 waves 2x4, 8-phase schedule ----
// LDS per (dbuf,op): 256 rows x 64 k bf16, elem(r,k) = r*64 + ((k>>3)^(r&7))*8
// + (k&7).  Halves: lo = rows 0..127 (16 KB contiguous), hi = rows 128..255.
// Waves: wm in {0,1} owns rows {64wm..64wm+63} u {128+64wm..}; wn in {0..3}
// owns cols {32wn..32wn+31} u {128+32wn..} so phase-0 reads exactly the lo
// halves.  Quadrants per K-tile: Q0=(rlo,clo) Q1=(rlo,chi) Q2=(rhi,clo)
// Q3=(rhi,chi) -> ds_read counts per phase 12/4/8/0.
template <int MODE>
__global__ __launch_bounds__(512, 2)
void gemm_fused(const unsigned short* __restrict__ A0,   // K=1024
                const unsigned short* __restrict__ A1,   // K=1024
                const unsigned short* __restrict__ A2,   // K=2048
                const unsigned short* __restrict__ B0T,
                const unsigned short* __restrict__ B1T,
                const unsigned short* __restrict__ B2T,
                const float* __restrict__ b0,
                const float* __restrict__ b1,
                const float* __restrict__ b2,
                const unsigned short* __restrict__ hb,   // h bf16 (R,S)
                const unsigned short* __restrict__ zb,   // z bf16 (S)
                float* __restrict__ outf,
                unsigned short* __restrict__ outb) {
  __shared__ unsigned short lds_s[65536];   // 128 KiB: [dbuf][A/B][16K elems]

  const int tid = threadIdx.x;
  const int bid = blockIdx.x;
  // XCD swizzle: 256 blocks, bid&7 = XCD; give each XCD 8 mBlks x 4 nBlks so
  // the 4 blocks sharing an A-slab are co-resident in one XCD's L2.
  const int swz = (bid & 7) * 32 + (bid >> 3);
  const int mBlk = swz >> 2;                 // 0..63
  const int nBlk = swz & 3;                  // 0..3
  const int rowBase = mBlk << 8;
  const int colBase = nBlk << 8;

  const int l = tid & 63;
  const int w = tid >> 6;                    // wave 0..7
  const int wm = w >> 2;                     // 0..1
  const int wn = w & 3;                      // 0..3
  const int lm = l & 15;
  const int quad = l >> 4;

  f32x4 acc[4][4][2];                        // [quadrant][fr][fc]
  #pragma unroll
  for (int q = 0; q < 4; ++q)
    #pragma unroll
    for (int fr = 0; fr < 4; ++fr)
      #pragma unroll
      for (int fc = 0; fc < 2; ++fc)
        acc[q][fr][fc] = (f32x4){0.f, 0.f, 0.f, 0.f};

  bf16x8 aF[4][2];        // A frags of current half (rows), [fr][ks]
  bf16x8 bLo[2][2];       // B frags lo cols, [fc][ks]
  bf16x8 bHi[2][2];       // B frags hi cols

  // stage one 16KB half-tile of K-tile kt (op: 0=A rows, 1=B cols; half 0/1).
  // 2 x global_load_lds dwordx4 per thread; LDS dest linear, global source
  // pre-swizzled (kg ^= row&7) so swizzled ds_read retrieves correct data.
  auto STAGE = [&](int kt, int op, int half) {
    const unsigned short* base;
    int K, kloc;
    if (kt < 16)      { base = op ? B0T : A0; K = 1024; kloc = kt << 6; }
    else if (kt < 32) { base = op ? B1T : A1; K = 1024; kloc = (kt - 16) << 6; }
    else              { base = op ? B2T : A2; K = 2048; kloc = (kt - 32) << 6; }
    const int rb = (op ? colBase : rowBase) + (half << 7);
    const unsigned short* g = base + (size_t)rb * K + kloc;
    unsigned short* lb = lds_s + ((kt & 1) << 15) + (op << 14) + (half << 13);
    #pragma unroll
    for (int j = 0; j < 2; ++j) {
      const int idx = (j << 9) + tid;        // 0..1023
      const int row = idx >> 3;              // 0..127 within half
      const int kg = (idx & 7) ^ (row & 7);  // swizzled source kgroup
      gload_lds16(g + (size_t)row * K + (kg << 3),
                  lb + ((idx & ~63) << 3));  // wave-uniform dest, +lane*16B HW
    }
  };

  auto LOAD_A = [&](int cb, int h) {
    #pragma unroll
    for (int fr = 0; fr < 4; ++fr) {
      const int r = wm * 64 + h * 128 + fr * 16 + lm;
      #pragma unroll
      for (int ks = 0; ks < 2; ++ks) {
        const int slot = ((ks << 2) | quad) ^ (lm & 7);
        aF[fr][ks] = *(const bf16x8*)(lds_s + cb + (r << 6) + (slot << 3));
      }
    }
  };
  auto LOAD_B = [&](int cb, int h, bf16x8 (&bv)[2][2]) {
    #pragma unroll
    for (int fc = 0; fc < 2; ++fc) {
      const int c = wn * 32 + h * 128 + fc * 16 + lm;
      #pragma unroll
      for (int ks = 0; ks < 2; ++ks) {
        const int slot = ((ks << 2) | quad) ^ (lm & 7);
        bv[fc][ks] = *(const bf16x8*)(lds_s + cb + 16384 + (c << 6) + (slot << 3));
      }
    }
  };
  auto MFMA16 = [&](f32x4 (&aq)[4][2], bf16x8 (&bv)[2][2]) {
    #pragma unroll
    for (int ks = 0; ks < 2; ++ks)
      #pragma unroll
      for (int fr = 0; fr < 4; ++fr)
        #pragma unroll
        for (int fc = 0; fc < 2; ++fc)
          aq[fr][fc] = __builtin_amdgcn_mfma_f32_16x16x32_bf16(
              aF[fr][ks], bv[fc][ks], aq[fr][fc], 0, 0, 0);
  };

  // ---- prologue: 7 half-tiles in flight; wait for tile0's 4 to land ----
  STAGE(0, 0, 0); STAGE(0, 1, 0); STAGE(0, 1, 1); STAGE(0, 0, 1);
  STAGE(1, 0, 0); STAGE(1, 1, 0); STAGE(1, 1, 1);
  WAIT_VM(6);
  BARRIER();

  // ---- main loop: 2 K-tiles / iteration, 8 phases.  NKT=64 -> 31 + peel ----
  #pragma unroll 1
  for (int i = 0; i < 31; ++i) {
    const int t1 = 2 * i + 1, t2 = 2 * i + 2, t3 = 2 * i + 3;
    // ph0: Q0 of tile 2i (buf0)
    LOAD_A(0, 0); LOAD_B(0, 0, bLo); STAGE(t1, 0, 1);
    BARRIER(); PRIO1(); MFMA16(acc[0], bLo); PRIO0(); BARRIER();
    // ph1: Q1
    LOAD_B(0, 1, bHi); STAGE(t2, 0, 0);
    BARRIER(); PRIO1(); MFMA16(acc[1], bHi); PRIO0(); BARRIER();
    // ph2: Q2
    LOAD_A(0, 1); STAGE(t2, 1, 0);
    BARRIER(); PRIO1(); MFMA16(acc[2], bLo); PRIO0(); BARRIER();
    // ph3: Q3 + counted vmcnt (tile 2i+1 complete, 3 half-tiles in flight)
    STAGE(t2, 1, 1);
    BARRIER(); PRIO1(); MFMA16(acc[3], bHi); PRIO0(); WAIT_VM(6); BARRIER();
    // ph4: Q0 of tile 2i+1 (buf1)
    LOAD_A(32768, 0); LOAD_B(32768, 0, bLo); STAGE(t2, 0, 1);
    BARRIER(); PRIO1(); MFMA16(acc[0], bLo); PRIO0(); BARRIER();
    // ph5: Q1
    LOAD_B(32768, 1, bHi); STAGE(t3, 0, 0);
    BARRIER(); PRIO1(); MFMA16(acc[1], bHi); PRIO0(); BARRIER();
    // ph6: Q2
    LOAD_A(32768, 1); STAGE(t3, 1, 0);
    BARRIER(); PRIO1(); MFMA16(acc[2], bLo); PRIO0(); BARRIER();
    // ph7: Q3 + counted vmcnt (tile 2i+2 complete)
    STAGE(t3, 1, 1);
    BARRIER(); PRIO1(); MFMA16(acc[3], bHi); PRIO0(); WAIT_VM(6); BARRIER();
  }
  // ---- peeled last iteration: tiles 62,63; only t63.Ahi left to stage ----
  LOAD_A(0, 0); LOAD_B(0, 0, bLo); STAGE(63, 0, 1);
  BARRIER(); PRIO1(); MFMA16(acc[0], bLo); PRIO0(); BARRIER();
  LOAD_B(0, 1, bHi);
  BARRIER(); PRIO1(); MFMA16(acc[1], bHi); PRIO0(); BARRIER();
  LOAD_A(0, 1);
  BARRIER(); PRIO1(); MFMA16(acc[2], bLo); PRIO0(); BARRIER();
  BARRIER(); PRIO1(); MFMA16(acc[3], bHi); PRIO0(); WAIT_VM(0); BARRIER();
  LOAD_A(32768, 0); LOAD_B(32768, 0, bLo);
  BARRIER(); PRIO1(); MFMA16(acc[0], bLo); PRIO0(); BARRIER();
  LOAD_B(32768, 1, bHi);
  BARRIER(); PRIO1(); MFMA16(acc[1], bHi); PRIO0(); BARRIER();
  LOAD_A(32768, 1);
  BARRIER(); PRIO1(); MFMA16(acc[2], bLo); PRIO0(); BARRIER();
  BARRIER(); PRIO1(); MFMA16(acc[3], bHi); PRIO0();

  // ---- fused epilogue. C/D layout: col = lane&15, row = quad*4 + reg ----
  #pragma unroll
  for (int q = 0; q < 4; ++q) {
    const int rQ = rowBase + wm * 64 + (q >> 1) * 128;
    const int cQ = colBase + wn * 32 + (q & 1) * 128;
    #pragma unroll
    for (int fc = 0; fc < 2; ++fc) {
      const int col = cQ + fc * 16 + lm;
      const float bias = b0[col] + b1[col] + b2[col];
      #pragma unroll
      for (int fr = 0; fr < 4; ++fr) {
        #pragma unroll
        for (int r = 0; r < 4; ++r) {
          const int row = rQ + fr * 16 + quad * 4 + r;
          const size_t idx = (size_t)row * 1024 + col;
          float v = acc[q][fr][fc][r] + bias;
          if constexpr (MODE == MODE_Z) {
            outb[idx] = f2bf(1.f / (1.f + __expf(-v)));
          } else if constexpr (MODE == MODE_R) {
            float rv = 1.f / (1.f + __expf(-v));
            outb[idx] = f2bf(rv * bf2f(hb[idx]));
          } else if constexpr (MODE == MODE_S) {
            float avv = fabsf(v);
            float e = __expf(-2.f * avv);
            float st = (1.f - e) / (1.f + e);      // |tanh|
            st = v < 0.f ? -st : st;
            float zv = bf2f(zb[idx]);
            float hv = bf2f(hb[idx]);
            float s = (1.f - zv) * hv + zv * st;
            outf[idx] = s;
            outb[idx] = f2bf(s);
          } else {  // MODE_T
            outf[idx] = v > 0.f ? v : 0.f;
          }
        }
      }
    }
  }
}

extern "C" void kernel_launch(void* const* d_in, const int* in_sizes, int n_in,
                              void* d_out, int out_size, void* d_ws, size_t ws_size,
                              hipStream_t stream) {
  (void)in_sizes; (void)n_in; (void)out_size; (void)ws_size;
  const float* x  = (const float*)d_in[0];   // [16384,1024]
  const float* h  = (const float*)d_in[1];   // [16384,1024]
  const float* a  = (const float*)d_in[2];   // [16384,2048]
  const float* W   = (const float*)d_in[3];  const float* bw  = (const float*)d_in[4];
  const float* Wz  = (const float*)d_in[5];  const float* bwz = (const float*)d_in[6];
  const float* Wr  = (const float*)d_in[7];  const float* bwr = (const float*)d_in[8];
  const float* U   = (const float*)d_in[9];  const float* bu  = (const float*)d_in[10];
  const float* Uz  = (const float*)d_in[11]; const float* buz = (const float*)d_in[12];
  const float* Ur  = (const float*)d_in[13]; const float* bur = (const float*)d_in[14];
  const float* C   = (const float*)d_in[15]; const float* bc  = (const float*)d_in[16];
  const float* Cz  = (const float*)d_in[17]; const float* bcz = (const float*)d_in[18];
  const float* Cr  = (const float*)d_in[19]; const float* bcr = (const float*)d_in[20];
  const float* Uo  = (const float*)d_in[21]; const float* buo = (const float*)d_in[22];
  const float* Vo  = (const float*)d_in[23]; const float* bvo = (const float*)d_in[24];
  const float* Co  = (const float*)d_in[25]; const float* bco = (const float*)d_in[26];

  const size_t M1 = 1024u * 1024u;           // 1M elements
  unsigned short* wsb = (unsigned short*)d_ws;
  // ws: 12 transposed bf16 weights (32 MB) + x_bf (32 MB) = 64 MB used.
  unsigned short* WzT = wsb + 0 * M1;
  unsigned short* UzT = wsb + 1 * M1;
  unsigned short* WrT = wsb + 2 * M1;
  unsigned short* UrT = wsb + 3 * M1;
  unsigned short* WT  = wsb + 4 * M1;
  unsigned short* UT  = wsb + 5 * M1;
  unsigned short* VoT = wsb + 6 * M1;
  unsigned short* UoT = wsb + 7 * M1;
  unsigned short* CzT = wsb + 8 * M1;        // 2M each from here
  unsigned short* CrT = wsb + 10 * M1;
  unsigned short* CT  = wsb + 12 * M1;
  unsigned short* CoT = wsb + 14 * M1;
  unsigned short* x_bf = wsb + 16 * M1;      // 16M elems

  // Scratch carved out of dead buffers (cross-launch ordering, see header):
  unsigned short* h_bf = (unsigned short*)((float*)d_out + 16 * M1); // d_out t-region
  unsigned short* a_bf = (unsigned short*)d_in[0];                   // x f32 dead after cvt_xh
  unsigned short* rh   = (unsigned short*)d_in[1];                   // h f32 dead after cvt_xh
  unsigned short* z_bf = (unsigned short*)d_in[1] + 16 * M1;
  unsigned short* s_bf = (unsigned short*)d_in[2];                   // a f32 dead after cvt_a

  float* s_out = (float*)d_out;
  float* t_out = (float*)d_out + 16 * M1;

  // 1) convert x,h (must precede a_bf overwriting x's buffer)
  cvt_xh<<<16384, 256, 0, stream>>>(x, h, x_bf, h_bf);
  // 2) convert a into x's (now dead) buffer
  cvt_a<<<16384, 256, 0, stream>>>(a, a_bf);
  // 3) all 12 weight transposes in one launch
  TArgs ta;
  const float* wsrc[12] = {Wz, Uz, Wr, Ur, W, U, Vo, Uo, Cz, Cr, C, Co};
  unsigned short* wdst[12] = {WzT, UzT, WrT, UrT, WT, UT, VoT, UoT, CzT, CrT, CT, CoT};
  for (int i = 0; i < 12; ++i) { ta.src[i] = wsrc[i]; ta.dst[i] = wdst[i]; }
  transpose_all<<<16384, dim3(32, 8), 0, stream>>>(ta);

  dim3 g(256), b(512);
  gemm_fused<MODE_R><<<g, b, 0, stream>>>(x_bf, h_bf, a_bf, WrT, UrT, CrT,
                                          bwr, bur, bcr, h_bf, nullptr, nullptr, rh);
  gemm_fused<MODE_Z><<<g, b, 0, stream>>>(x_bf, h_bf, a_bf, WzT, UzT, CzT,
                                          bwz, buz, bcz, nullptr, nullptr, nullptr, z_bf);
  gemm_fused<MODE_S><<<g, b, 0, stream>>>(x_bf, rh, a_bf, WT, UT, CT,
                                          bw, bu, bc, h_bf, z_bf, s_out, s_bf);
  gemm_fused<MODE_T><<<g, b, 0, stream>>>(x_bf, s_bf, a_bf, VoT, UoT, CoT,
                                          bvo, buo, bco, nullptr, nullptr, t_out, nullptr);
}

// Round 2
// 1389.202 us; speedup vs baseline: 1.1028x; 1.1028x over previous
//
#include <hip/hip_runtime.h>
#include <stdint.h>
#include <stddef.h>

// AttentionGRUCell on MI355X (gfx950).  B=16384, EMB=1024, HID=1024, COMB=2048.
// All GEMMs bf16 MFMA 16x16x32.  256x256-tile 8-phase schedule (m201 template):
// BK=64, 512 threads (8 waves, 2Mx4N), 128 KiB double-buffered LDS, one
// half-tile (16 KB) staged per phase via global_load_lds dwordx4, counted
// s_waitcnt vmcnt(6) only twice per iteration (3 half-tiles in flight).
//
// ROUND-2 FIX: barriers are __builtin_amdgcn_s_barrier() and waitcnt asm has
// NO "memory" clobber.  The previous revision used asm("s_barrier":::"memory")
// which makes SIInsertWaitcnts treat every barrier as may-access-all-memory
// and emit s_waitcnt vmcnt(0) before each of the 16 barriers/iter -> full
// latency drain per phase (measured 336us/GEMM, MfmaUtil 16.8%).  Ordering
// safety now comes from sched_barrier(0) fences at buffer-flip points and a
// compiler-only memory fence before the epilogue (keeps LICM from hoisting
// epilogue loads above the counted vmcnt waits).
//
// Memory choreography (cross-launch ordering makes input buffers reusable):
//   cvt_xh : x,h f32 -> x_bf (ws), h_bf (d_out t-region, dead until T)
//   cvt_a  : a f32   -> a_bf (x's input buffer, x f32 now dead)
//   transpose_all: 12 weights f32 [K,N] -> bf16 [N,K] in ws
//   R: rh = sigmoid(xWr+hUr+aCr)*h -> h-buffer[0:32M)      (h f32 dead)
//   Z: z  = sigmoid(xWz+hUz+aCz)   -> h-buffer[32M:64M)
//   S: s  = (1-z)h + z*tanh(xW+rhU+aC) -> d_out[0:64MB) f32, s_bf -> a-buffer
//   T: t  = relu(xVo+sUo+aCo)      -> d_out[64MB:128MB) f32 (over dead h_bf)

#define MODE_Z 0
#define MODE_R 1
#define MODE_S 2
#define MODE_T 3

typedef __attribute__((ext_vector_type(8))) __bf16 bf16x8;
typedef __attribute__((ext_vector_type(4))) float f32x4;
typedef __attribute__((ext_vector_type(8))) unsigned short us8;

__device__ __forceinline__ unsigned short f2bf(float f) {
  union { float f; unsigned u; } v; v.f = f;
  unsigned r = 0x7FFFu + ((v.u >> 16) & 1u);   // round-to-nearest-even
  return (unsigned short)((v.u + r) >> 16);
}
__device__ __forceinline__ float bf2f(unsigned short h) {
  union { unsigned u; float f; } v; v.u = ((unsigned)h) << 16;
  return v.f;
}

__device__ __forceinline__ void gload_lds16(const unsigned short* g, unsigned short* l) {
  __builtin_amdgcn_global_load_lds(
      (const __attribute__((address_space(1))) void*)g,
      (__attribute__((address_space(3))) void*)l, 16, 0, 0);
}

// ---- f32 -> bf16 converters (8 elems/thread, fully coalesced) ----
__global__ void cvt_xh(const float* __restrict__ x, const float* __restrict__ h,
                       unsigned short* __restrict__ xb, unsigned short* __restrict__ hb) {
  const size_t NX = 16777216;  // 16384*1024
  size_t i = ((size_t)blockIdx.x * 256 + threadIdx.x) * 8;
  const float* s; unsigned short* d; size_t off;
  if (i < NX) { s = x; d = xb; off = i; } else { s = h; d = hb; off = i - NX; }
  f32x4 v0 = *(const f32x4*)(s + off);
  f32x4 v1 = *(const f32x4*)(s + off + 4);
  us8 p = { f2bf(v0.x), f2bf(v0.y), f2bf(v0.z), f2bf(v0.w),
            f2bf(v1.x), f2bf(v1.y), f2bf(v1.z), f2bf(v1.w) };
  *(us8*)(d + off) = p;
}

__global__ void cvt_a(const float* __restrict__ a, unsigned short* __restrict__ ab) {
  size_t i = ((size_t)blockIdx.x * 256 + threadIdx.x) * 8;
  f32x4 v0 = *(const f32x4*)(a + i);
  f32x4 v1 = *(const f32x4*)(a + i + 4);
  us8 p = { f2bf(v0.x), f2bf(v0.y), f2bf(v0.z), f2bf(v0.w),
            f2bf(v1.x), f2bf(v1.y), f2bf(v1.z), f2bf(v1.w) };
  *(us8*)(ab + i) = p;
}

// ---- batched weight transpose: f32 [K,1024] -> bf16 [1024,K] ----
struct TArgs {
  const float* src[12];
  unsigned short* dst[12];
};

__global__ void transpose_all(TArgs ta) {
  __shared__ float tile[32][33];
  int t = blockIdx.x;
  int w, K, local;
  if (t < 8192) { w = t >> 10; K = 1024; local = t & 1023; }
  else { int t2 = t - 8192; w = 8 + (t2 >> 11); K = 2048; local = t2 & 2047; }
  int kb = (K == 1024) ? ((local & 31) << 5) : ((local & 63) << 5);
  int nb = (K == 1024) ? ((local >> 5) << 5) : ((local >> 6) << 5);
  const float* src = ta.src[w];
  unsigned short* dst = ta.dst[w];
  int tx = threadIdx.x, ty = threadIdx.y;   // block 32x8
  #pragma unroll
  for (int i = 0; i < 32; i += 8)
    tile[ty + i][tx] = src[(size_t)(kb + ty + i) * 1024 + nb + tx];
  __syncthreads();
  #pragma unroll
  for (int i = 0; i < 32; i += 8)
    dst[(size_t)(nb + ty + i) * K + kb + tx] = f2bf(tile[tx][ty + i]);
}

// Raw barrier (no implicit waitcnt drain) + clobber-free counted waits.
#define BARRIER()     __builtin_amdgcn_s_barrier()
#define WAIT_VM(N)    asm volatile("s_waitcnt vmcnt(" #N ")")
#define SCHED_FENCE() __builtin_amdgcn_sched_barrier(0)
#define PRIO1()       __builtin_amdgcn_s_setprio(1)
#define PRIO0()       __builtin_amdgcn_s_setprio(0)

// ---- fused GEMM: 256x256 tile, 8 waves 2x4, 8-phase schedule ----
// LDS per (dbuf,op): 256 rows x 64 k bf16, elem(r,k) = r*64 + ((k>>3)^(r&7))*8
// + (k&7).  Halves: lo = rows 0..127 (16 KB contiguous), hi = rows 128..255.
// Quadrants per K-tile: Q0=(rlo,clo) Q1=(rlo,chi) Q2=(rhi,clo) Q3=(rhi,chi)
// -> ds_read counts per phase 12/4/8/0.
template <int MODE>
__global__ __launch_bounds__(512, 2)
void gemm_fused(const unsigned short* __restrict__ A0,   // K=1024
                const unsigned short* __restrict__ A1,   // K=1024
                const unsigned short* __restrict__ A2,   // K=2048
                const unsigned short* __restrict__ B0T,
                const unsigned short* __restrict__ B1T,
                const unsigned short* __restrict__ B2T,
                const float* __restrict__ b0,
                const float* __restrict__ b1,
                const float* __restrict__ b2,
                const unsigned short* __restrict__ hb,   // h bf16 (R,S)
                const unsigned short* __restrict__ zb,   // z bf16 (S)
                float* __restrict__ outf,
                unsigned short* __restrict__ outb) {
  __shared__ unsigned short lds_s[65536];   // 128 KiB: [dbuf][A/B][16K elems]

  const int tid = threadIdx.x;
  const int bid = blockIdx.x;
  // XCD swizzle: 256 blocks, bid&7 = XCD; give each XCD 8 mBlks x 4 nBlks so
  // the 4 blocks sharing an A-slab are co-resident in one XCD's L2.
  const int swz = (bid & 7) * 32 + (bid >> 3);
  const int mBlk = swz >> 2;                 // 0..63
  const int nBlk = swz & 3;                  // 0..3
  const int rowBase = mBlk << 8;
  const int colBase = nBlk << 8;

  const int l = tid & 63;
  const int w = tid >> 6;                    // wave 0..7
  const int wm = w >> 2;                     // 0..1
  const int wn = w & 3;                      // 0..3
  const int lm = l & 15;
  const int quad = l >> 4;

  f32x4 acc[4][4][2];                        // [quadrant][fr][fc]
  #pragma unroll
  for (int q = 0; q < 4; ++q)
    #pragma unroll
    for (int fr = 0; fr < 4; ++fr)
      #pragma unroll
      for (int fc = 0; fc < 2; ++fc)
        acc[q][fr][fc] = (f32x4){0.f, 0.f, 0.f, 0.f};

  bf16x8 aF[4][2];        // A frags of current half (rows), [fr][ks]
  bf16x8 bLo[2][2];       // B frags lo cols, [fc][ks]
  bf16x8 bHi[2][2];       // B frags hi cols

  // stage one 16KB half-tile of K-tile kt (op: 0=A rows, 1=B cols; half 0/1).
  // 2 x global_load_lds dwordx4 per thread; LDS dest linear, global source
  // pre-swizzled (kg ^= row&7) so swizzled ds_read retrieves correct data.
  auto STAGE = [&](int kt, int op, int half) {
    const unsigned short* base;
    int K, kloc;
    if (kt < 16)      { base = op ? B0T : A0; K = 1024; kloc = kt << 6; }
    else if (kt < 32) { base = op ? B1T : A1; K = 1024; kloc = (kt - 16) << 6; }
    else              { base = op ? B2T : A2; K = 2048; kloc = (kt - 32) << 6; }
    const int rb = (op ? colBase : rowBase) + (half << 7);
    const unsigned short* g = base + (size_t)rb * K + kloc;
    unsigned short* lb = lds_s + ((kt & 1) << 15) + (op << 14) + (half << 13);
    #pragma unroll
    for (int j = 0; j < 2; ++j) {
      const int idx = (j << 9) + tid;        // 0..1023
      const int row = idx >> 3;              // 0..127 within half
      const int kg = (idx & 7) ^ (row & 7);  // swizzled source kgroup
      gload_lds16(g + (size_t)row * K + (kg << 3),
                  lb + ((idx & ~63) << 3));  // wave-uniform dest, +lane*16B HW
    }
  };

  auto LOAD_A = [&](int cb, int h) {
    #pragma unroll
    for (int fr = 0; fr < 4; ++fr) {
      const int r = wm * 64 + h * 128 + fr * 16 + lm;
      #pragma unroll
      for (int ks = 0; ks < 2; ++ks) {
        const int slot = ((ks << 2) | quad) ^ (lm & 7);
        aF[fr][ks] = *(const bf16x8*)(lds_s + cb + (r << 6) + (slot << 3));
      }
    }
  };
  auto LOAD_B = [&](int cb, int h, bf16x8 (&bv)[2][2]) {
    #pragma unroll
    for (int fc = 0; fc < 2; ++fc) {
      const int c = wn * 32 + h * 128 + fc * 16 + lm;
      #pragma unroll
      for (int ks = 0; ks < 2; ++ks) {
        const int slot = ((ks << 2) | quad) ^ (lm & 7);
        bv[fc][ks] = *(const bf16x8*)(lds_s + cb + 16384 + (c << 6) + (slot << 3));
      }
    }
  };
  auto MFMA16 = [&](f32x4 (&aq)[4][2], bf16x8 (&bv)[2][2]) {
    #pragma unroll
    for (int ks = 0; ks < 2; ++ks)
      #pragma unroll
      for (int fr = 0; fr < 4; ++fr)
        #pragma unroll
        for (int fc = 0; fc < 2; ++fc)
          aq[fr][fc] = __builtin_amdgcn_mfma_f32_16x16x32_bf16(
              aF[fr][ks], bv[fc][ks], aq[fr][fc], 0, 0, 0);
  };

  // ---- prologue: 7 half-tiles in flight; wait for tile0's 4 to land ----
  STAGE(0, 0, 0); STAGE(0, 1, 0); STAGE(0, 1, 1); STAGE(0, 0, 1);
  STAGE(1, 0, 0); STAGE(1, 1, 0); STAGE(1, 1, 1);
  WAIT_VM(6);
  BARRIER();

  // ---- main loop: 2 K-tiles / iteration, 8 phases.  NKT=64 -> 31 + peel ----
  #pragma unroll 1
  for (int i = 0; i < 31; ++i) {
    const int t1 = 2 * i + 1, t2 = 2 * i + 2, t3 = 2 * i + 3;
    SCHED_FENCE();                            // buf0 reads stay after flip wait
    // ph0: Q0 of tile 2i (buf0)
    LOAD_A(0, 0); LOAD_B(0, 0, bLo); STAGE(t1, 0, 1);
    BARRIER(); PRIO1(); MFMA16(acc[0], bLo); PRIO0(); BARRIER();
    // ph1: Q1
    LOAD_B(0, 1, bHi); STAGE(t2, 0, 0);
    BARRIER(); PRIO1(); MFMA16(acc[1], bHi); PRIO0(); BARRIER();
    // ph2: Q2
    LOAD_A(0, 1); STAGE(t2, 1, 0);
    BARRIER(); PRIO1(); MFMA16(acc[2], bLo); PRIO0(); BARRIER();
    // ph3: Q3 + counted vmcnt (tile 2i+1 complete, 3 half-tiles in flight)
    STAGE(t2, 1, 1);
    BARRIER(); PRIO1(); MFMA16(acc[3], bHi); PRIO0(); WAIT_VM(6); BARRIER();
    SCHED_FENCE();                            // buf1 reads stay after flip wait
    // ph4: Q0 of tile 2i+1 (buf1)
    LOAD_A(32768, 0); LOAD_B(32768, 0, bLo); STAGE(t2, 0, 1);
    BARRIER(); PRIO1(); MFMA16(acc[0], bLo); PRIO0(); BARRIER();
    // ph5: Q1
    LOAD_B(32768, 1, bHi); STAGE(t3, 0, 0);
    BARRIER(); PRIO1(); MFMA16(acc[1], bHi); PRIO0(); BARRIER();
    // ph6: Q2
    LOAD_A(32768, 1); STAGE(t3, 1, 0);
    BARRIER(); PRIO1(); MFMA16(acc[2], bLo); PRIO0(); BARRIER();
    // ph7: Q3 + counted vmcnt (tile 2i+2 complete)
    STAGE(t3, 1, 1);
    BARRIER(); PRIO1(); MFMA16(acc[3], bHi); PRIO0(); WAIT_VM(6); BARRIER();
  }
  // ---- peeled last iteration: tiles 62,63; only t63.Ahi left to stage ----
  SCHED_FENCE();
  LOAD_A(0, 0); LOAD_B(0, 0, bLo); STAGE(63, 0, 1);
  BARRIER(); PRIO1(); MFMA16(acc[0], bLo); PRIO0(); BARRIER();
  LOAD_B(0, 1, bHi);
  BARRIER(); PRIO1(); MFMA16(acc[1], bHi); PRIO0(); BARRIER();
  LOAD_A(0, 1);
  BARRIER(); PRIO1(); MFMA16(acc[2], bLo); PRIO0(); BARRIER();
  BARRIER(); PRIO1(); MFMA16(acc[3], bHi); PRIO0(); WAIT_VM(0); BARRIER();
  SCHED_FENCE();
  LOAD_A(32768, 0); LOAD_B(32768, 0, bLo);
  BARRIER(); PRIO1(); MFMA16(acc[0], bLo); PRIO0(); BARRIER();
  LOAD_B(32768, 1, bHi);
  BARRIER(); PRIO1(); MFMA16(acc[1], bHi); PRIO0(); BARRIER();
  LOAD_A(32768, 1);
  BARRIER(); PRIO1(); MFMA16(acc[2], bLo); PRIO0(); BARRIER();
  BARRIER(); PRIO1(); MFMA16(acc[3], bHi); PRIO0();

  // Compiler-only fence: keep epilogue global loads (bias/hb/zb) from being
  // hoisted above the counted vmcnt waits (would skew vmcnt(N) semantics).
  asm volatile("" ::: "memory");

  // ---- fused epilogue. C/D layout: col = lane&15, row = quad*4 + reg ----
  #pragma unroll
  for (int q = 0; q < 4; ++q) {
    const int rQ = rowBase + wm * 64 + (q >> 1) * 128;
    const int cQ = colBase + wn * 32 + (q & 1) * 128;
    #pragma unroll
    for (int fc = 0; fc < 2; ++fc) {
      const int col = cQ + fc * 16 + lm;
      const float bias = b0[col] + b1[col] + b2[col];
      #pragma unroll
      for (int fr = 0; fr < 4; ++fr) {
        #pragma unroll
        for (int r = 0; r < 4; ++r) {
          const int row = rQ + fr * 16 + quad * 4 + r;
          const size_t idx = (size_t)row * 1024 + col;
          float v = acc[q][fr][fc][r] + bias;
          if constexpr (MODE == MODE_Z) {
            outb[idx] = f2bf(1.f / (1.f + __expf(-v)));
          } else if constexpr (MODE == MODE_R) {
            float rv = 1.f / (1.f + __expf(-v));
            outb[idx] = f2bf(rv * bf2f(hb[idx]));
          } else if constexpr (MODE == MODE_S) {
            float avv = fabsf(v);
            float e = __expf(-2.f * avv);
            float st = (1.f - e) / (1.f + e);      // |tanh|
            st = v < 0.f ? -st : st;
            float zv = bf2f(zb[idx]);
            float hv = bf2f(hb[idx]);
            float s = (1.f - zv) * hv + zv * st;
            outf[idx] = s;
            outb[idx] = f2bf(s);
          } else {  // MODE_T
            outf[idx] = v > 0.f ? v : 0.f;
          }
        }
      }
    }
  }
}

extern "C" void kernel_launch(void* const* d_in, const int* in_sizes, int n_in,
                              void* d_out, int out_size, void* d_ws, size_t ws_size,
                              hipStream_t stream) {
  (void)in_sizes; (void)n_in; (void)out_size; (void)ws_size;
  const float* x  = (const float*)d_in[0];   // [16384,1024]
  const float* h  = (const float*)d_in[1];   // [16384,1024]
  const float* a  = (const float*)d_in[2];   // [16384,2048]
  const float* W   = (const float*)d_in[3];  const float* bw  = (const float*)d_in[4];
  const float* Wz  = (const float*)d_in[5];  const float* bwz = (const float*)d_in[6];
  const float* Wr  = (const float*)d_in[7];  const float* bwr = (const float*)d_in[8];
  const float* U   = (const float*)d_in[9];  const float* bu  = (const float*)d_in[10];
  const float* Uz  = (const float*)d_in[11]; const float* buz = (const float*)d_in[12];
  const float* Ur  = (const float*)d_in[13]; const float* bur = (const float*)d_in[14];
  const float* C   = (const float*)d_in[15]; const float* bc  = (const float*)d_in[16];
  const float* Cz  = (const float*)d_in[17]; const float* bcz = (const float*)d_in[18];
  const float* Cr  = (const float*)d_in[19]; const float* bcr = (const float*)d_in[20];
  const float* Uo  = (const float*)d_in[21]; const float* buo = (const float*)d_in[22];
  const float* Vo  = (const float*)d_in[23]; const float* bvo = (const float*)d_in[24];
  const float* Co  = (const float*)d_in[25]; const float* bco = (const float*)d_in[26];

  const size_t M1 = 1024u * 1024u;           // 1M elements
  unsigned short* wsb = (unsigned short*)d_ws;
  // ws: 12 transposed bf16 weights (32 MB) + x_bf (32 MB) = 64 MB used.
  unsigned short* WzT = wsb + 0 * M1;
  unsigned short* UzT = wsb + 1 * M1;
  unsigned short* WrT = wsb + 2 * M1;
  unsigned short* UrT = wsb + 3 * M1;
  unsigned short* WT  = wsb + 4 * M1;
  unsigned short* UT  = wsb + 5 * M1;
  unsigned short* VoT = wsb + 6 * M1;
  unsigned short* UoT = wsb + 7 * M1;
  unsigned short* CzT = wsb + 8 * M1;        // 2M each from here
  unsigned short* CrT = wsb + 10 * M1;
  unsigned short* CT  = wsb + 12 * M1;
  unsigned short* CoT = wsb + 14 * M1;
  unsigned short* x_bf = wsb + 16 * M1;      // 16M elems

  // Scratch carved out of dead buffers (cross-launch ordering, see header):
  unsigned short* h_bf = (unsigned short*)((float*)d_out + 16 * M1); // d_out t-region
  unsigned short* a_bf = (unsigned short*)d_in[0];                   // x f32 dead after cvt_xh
  unsigned short* rh   = (unsigned short*)d_in[1];                   // h f32 dead after cvt_xh
  unsigned short* z_bf = (unsigned short*)d_in[1] + 16 * M1;
  unsigned short* s_bf = (unsigned short*)d_in[2];                   // a f32 dead after cvt_a

  float* s_out = (float*)d_out;
  float* t_out = (float*)d_out + 16 * M1;

  // 1) convert x,h (must precede a_bf overwriting x's buffer)
  cvt_xh<<<16384, 256, 0, stream>>>(x, h, x_bf, h_bf);
  // 2) convert a into x's (now dead) buffer
  cvt_a<<<16384, 256, 0, stream>>>(a, a_bf);
  // 3) all 12 weight transposes in one launch
  TArgs ta;
  const float* wsrc[12] = {Wz, Uz, Wr, Ur, W, U, Vo, Uo, Cz, Cr, C, Co};
  unsigned short* wdst[12] = {WzT, UzT, WrT, UrT, WT, UT, VoT, UoT, CzT, CrT, CT, CoT};
  for (int i = 0; i < 12; ++i) { ta.src[i] = wsrc[i]; ta.dst[i] = wdst[i]; }
  transpose_all<<<16384, dim3(32, 8), 0, stream>>>(ta);

  dim3 g(256), b(512);
  gemm_fused<MODE_R><<<g, b, 0, stream>>>(x_bf, h_bf, a_bf, WrT, UrT, CrT,
                                          bwr, bur, bcr, h_bf, nullptr, nullptr, rh);
  gemm_fused<MODE_Z><<<g, b, 0, stream>>>(x_bf, h_bf, a_bf, WzT, UzT, CzT,
                                          bwz, buz, bcz, nullptr, nullptr, nullptr, z_bf);
  gemm_fused<MODE_S><<<g, b, 0, stream>>>(x_bf, rh, a_bf, WT, UT, CT,
                                          bw, bu, bc, h_bf, z_bf, s_out, s_bf);
  gemm_fused<MODE_T><<<g, b, 0, stream>>>(x_bf, s_bf, a_bf, VoT, UoT, CoT,
                                          bvo, buo, bco, nullptr, nullptr, t_out, nullptr);
}

// Round 4
// 997.406 us; speedup vs baseline: 1.5361x; 1.3928x over previous
//
#include <hip/hip_runtime.h>
#include <stdint.h>
#include <stddef.h>

// AttentionGRUCell on MI355X (gfx950).  B=16384, EMB=1024, HID=1024, COMB=2048.
// 256x256-tile 8-phase GEMM (m201 template): BK=64, 512 threads (8 waves 2Mx4N),
// 128 KiB double-buffered LDS, one 16KB half-tile staged per phase via
// global_load_lds dwordx4, counted s_waitcnt vmcnt(6) twice per iteration.
//
// ROUND-4: resubmission of round-3 (container-level infra failure, no pytest
// ran).  Kernel audited: barrier counts uniform, LDS offsets in-bounds,
// stage/read choreography race-free (identical to the numerically-passing
// round-2 schedule; only the fragment-read mechanism changed).
//
// ROUND-3 FIX under test: fragment loads are inline-asm ds_read_b128.  With
// IR-level LDS loads, LLVM must order them against the in-flight
// global_load_lds LDS writes (alias-unprovable XOR'd addresses) and inserts
// s_waitcnt vmcnt(0) before every ds_read cluster -> full latency drain per
// phase (measured 283us/GEMM, 65% idle).  Opaque asm ds_reads + explicit
// per-phase {barrier; lgkmcnt(0); sched_barrier(0)} (rule #18) restore the
// counted-vmcnt pipeline.  Runtime LDS write/read ordering is guaranteed by
// the vmcnt(6) discipline (a tile's staging completes >=1 K-tile before its
// reads; overwrites gated by the barrier pair of the preceding phase).
//
// Memory choreography (cross-launch ordering makes input buffers reusable):
//   cvt_xh : x,h f32 -> x_bf (ws), h_bf (d_out t-region, dead until T)
//   cvt_a  : a f32   -> a_bf (x's input buffer, x f32 now dead)
//   transpose_all: 12 weights f32 [K,N] -> bf16 [N,K] in ws
//   R: rh = sigmoid(xWr+hUr+aCr)*h -> h-buffer[0:32M)      (h f32 dead)
//   Z: z  = sigmoid(xWz+hUz+aCz)   -> h-buffer[32M:64M)
//   S: s  = (1-z)h + z*tanh(xW+rhU+aC) -> d_out[0:64MB) f32, s_bf -> a-buffer
//   T: t  = relu(xVo+sUo+aCo)      -> d_out[64MB:128MB) f32 (over dead h_bf)

#define MODE_Z 0
#define MODE_R 1
#define MODE_S 2
#define MODE_T 3

typedef __attribute__((ext_vector_type(8))) __bf16 bf16x8;
typedef __attribute__((ext_vector_type(4))) float f32x4;
typedef __attribute__((ext_vector_type(8))) unsigned short us8;

__device__ __forceinline__ unsigned short f2bf(float f) {
  union { float f; unsigned u; } v; v.f = f;
  unsigned r = 0x7FFFu + ((v.u >> 16) & 1u);   // round-to-nearest-even
  return (unsigned short)((v.u + r) >> 16);
}
__device__ __forceinline__ float bf2f(unsigned short h) {
  union { unsigned u; float f; } v; v.u = ((unsigned)h) << 16;
  return v.f;
}

__device__ __forceinline__ void gload_lds16(const unsigned short* g, unsigned short* l) {
  __builtin_amdgcn_global_load_lds(
      (const __attribute__((address_space(1))) void*)g,
      (__attribute__((address_space(3))) void*)l, 16, 0, 0);
}

// Opaque LDS read: compiler cannot alias-order it against global_load_lds
// writes, so no conservative vmcnt(0) gets inserted.  off = LDS byte offset.
__device__ __forceinline__ bf16x8 dsr128(unsigned off) {
  bf16x8 r;
  asm volatile("ds_read_b128 %0, %1" : "=v"(r) : "v"(off));
  return r;
}

// ---- f32 -> bf16 converters (8 elems/thread, fully coalesced) ----
__global__ void cvt_xh(const float* __restrict__ x, const float* __restrict__ h,
                       unsigned short* __restrict__ xb, unsigned short* __restrict__ hb) {
  const size_t NX = 16777216;  // 16384*1024
  size_t i = ((size_t)blockIdx.x * 256 + threadIdx.x) * 8;
  const float* s; unsigned short* d; size_t off;
  if (i < NX) { s = x; d = xb; off = i; } else { s = h; d = hb; off = i - NX; }
  f32x4 v0 = *(const f32x4*)(s + off);
  f32x4 v1 = *(const f32x4*)(s + off + 4);
  us8 p = { f2bf(v0.x), f2bf(v0.y), f2bf(v0.z), f2bf(v0.w),
            f2bf(v1.x), f2bf(v1.y), f2bf(v1.z), f2bf(v1.w) };
  *(us8*)(d + off) = p;
}

__global__ void cvt_a(const float* __restrict__ a, unsigned short* __restrict__ ab) {
  size_t i = ((size_t)blockIdx.x * 256 + threadIdx.x) * 8;
  f32x4 v0 = *(const f32x4*)(a + i);
  f32x4 v1 = *(const f32x4*)(a + i + 4);
  us8 p = { f2bf(v0.x), f2bf(v0.y), f2bf(v0.z), f2bf(v0.w),
            f2bf(v1.x), f2bf(v1.y), f2bf(v1.z), f2bf(v1.w) };
  *(us8*)(ab + i) = p;
}

// ---- batched weight transpose: f32 [K,1024] -> bf16 [1024,K] ----
struct TArgs {
  const float* src[12];
  unsigned short* dst[12];
};

__global__ void transpose_all(TArgs ta) {
  __shared__ float tile[32][33];
  int t = blockIdx.x;
  int w, K, local;
  if (t < 8192) { w = t >> 10; K = 1024; local = t & 1023; }
  else { int t2 = t - 8192; w = 8 + (t2 >> 11); K = 2048; local = t2 & 2047; }
  int kb = (K == 1024) ? ((local & 31) << 5) : ((local & 63) << 5);
  int nb = (K == 1024) ? ((local >> 5) << 5) : ((local >> 6) << 5);
  const float* src = ta.src[w];
  unsigned short* dst = ta.dst[w];
  int tx = threadIdx.x, ty = threadIdx.y;   // block 32x8
  #pragma unroll
  for (int i = 0; i < 32; i += 8)
    tile[ty + i][tx] = src[(size_t)(kb + ty + i) * 1024 + nb + tx];
  __syncthreads();
  #pragma unroll
  for (int i = 0; i < 32; i += 8)
    dst[(size_t)(nb + ty + i) * K + kb + tx] = f2bf(tile[tx][ty + i]);
}

#define BARRIER()     __builtin_amdgcn_s_barrier()
#define WAIT_VM(N)    asm volatile("s_waitcnt vmcnt(" #N ")")
// rule #18: explicit lgkmcnt for asm ds_reads + sched fence so MFMA can't hoist
#define WAIT_LGKM0()  do { asm volatile("s_waitcnt lgkmcnt(0)"); \
                           __builtin_amdgcn_sched_barrier(0); } while (0)
#define PRIO1()       __builtin_amdgcn_s_setprio(1)
#define PRIO0()       __builtin_amdgcn_s_setprio(0)

// ---- fused GEMM: 256x256 tile, 8 waves 2x4, 8-phase schedule ----
// LDS bytes per dbuf: A at [0,32768), B at [32768,65536); dbuf1 at +65536.
// elem(r,k): byte = r*128 + (slot)*16 + (k&7)*2, slot = (k>>3)^(r&7).
// Quadrants per K-tile: Q0=(rlo,clo) Q1=(rlo,chi) Q2=(rhi,clo) Q3=(rhi,chi).
template <int MODE>
__global__ __launch_bounds__(512, 2)
void gemm_fused(const unsigned short* __restrict__ A0,   // K=1024
                const unsigned short* __restrict__ A1,   // K=1024
                const unsigned short* __restrict__ A2,   // K=2048
                const unsigned short* __restrict__ B0T,
                const unsigned short* __restrict__ B1T,
                const unsigned short* __restrict__ B2T,
                const float* __restrict__ b0,
                const float* __restrict__ b1,
                const float* __restrict__ b2,
                const unsigned short* __restrict__ hb,   // h bf16 (R,S)
                const unsigned short* __restrict__ zb,   // z bf16 (S)
                float* __restrict__ outf,
                unsigned short* __restrict__ outb) {
  __shared__ unsigned short lds_s[65536];   // 128 KiB

  const int tid = threadIdx.x;
  const int bid = blockIdx.x;
  // XCD swizzle: 256 blocks, bid&7 = XCD; each XCD gets 8 mBlks x 4 nBlks so
  // the 4 blocks sharing an A-slab are co-resident in one XCD's L2.
  const int swz = (bid & 7) * 32 + (bid >> 3);
  const int mBlk = swz >> 2;                 // 0..63
  const int nBlk = swz & 3;                  // 0..3
  const int rowBase = mBlk << 8;
  const int colBase = nBlk << 8;

  const int l = tid & 63;
  const int w = tid >> 6;                    // wave 0..7
  const int wm = w >> 2;                     // 0..1
  const int wn = w & 3;                      // 0..3
  const int lm = l & 15;
  const int quad = l >> 4;

  // LDS byte-offset bases for fragment reads
  const unsigned lmq = (unsigned)(lm & 7);
  const unsigned sB0 = ((unsigned)quad ^ lmq) << 4;          // ks=0 slot*16
  const unsigned sB1 = (((unsigned)quad | 4u) ^ lmq) << 4;   // ks=1 slot*16
  const unsigned aBase = (unsigned)(wm * 8192 + lm * 128);
  const unsigned bBase = 32768u + (unsigned)(wn * 4096 + lm * 128);

  f32x4 acc[4][4][2];                        // [quadrant][fr][fc]
  #pragma unroll
  for (int q = 0; q < 4; ++q)
    #pragma unroll
    for (int fr = 0; fr < 4; ++fr)
      #pragma unroll
      for (int fc = 0; fc < 2; ++fc)
        acc[q][fr][fc] = (f32x4){0.f, 0.f, 0.f, 0.f};

  bf16x8 aF[4][2];        // A frags of current half (rows), [fr][ks]
  bf16x8 bLo[2][2];       // B frags lo cols, [fc][ks]
  bf16x8 bHi[2][2];       // B frags hi cols

  // stage one 16KB half-tile of K-tile kt (op: 0=A rows, 1=B cols; half 0/1).
  auto STAGE = [&](int kt, int op, int half) {
    const unsigned short* base;
    int K, kloc;
    if (kt < 16)      { base = op ? B0T : A0; K = 1024; kloc = kt << 6; }
    else if (kt < 32) { base = op ? B1T : A1; K = 1024; kloc = (kt - 16) << 6; }
    else              { base = op ? B2T : A2; K = 2048; kloc = (kt - 32) << 6; }
    const int rb = (op ? colBase : rowBase) + (half << 7);
    const unsigned short* g = base + (size_t)rb * K + kloc;
    unsigned short* lb = lds_s + ((kt & 1) << 15) + (op << 14) + (half << 13);
    #pragma unroll
    for (int j = 0; j < 2; ++j) {
      const int idx = (j << 9) + tid;        // 0..1023
      const int row = idx >> 3;              // 0..127 within half
      const int kg = (idx & 7) ^ (row & 7);  // swizzled source kgroup
      gload_lds16(g + (size_t)row * K + (kg << 3),
                  lb + ((idx & ~63) << 3));  // wave-uniform dest, +lane*16B HW
    }
  };

  // d = dbuf byte base (0 or 65536)
  auto LOAD_A = [&](unsigned d, int h) {
    #pragma unroll
    for (int fr = 0; fr < 4; ++fr) {
      const unsigned o = d + aBase + (unsigned)(h << 14) + (unsigned)(fr << 11);
      aF[fr][0] = dsr128(o + sB0);
      aF[fr][1] = dsr128(o + sB1);
    }
  };
  auto LOAD_B = [&](unsigned d, int h, bf16x8 (&bv)[2][2]) {
    #pragma unroll
    for (int fc = 0; fc < 2; ++fc) {
      const unsigned o = d + bBase + (unsigned)(h << 14) + (unsigned)(fc << 11);
      bv[fc][0] = dsr128(o + sB0);
      bv[fc][1] = dsr128(o + sB1);
    }
  };
  auto MFMA16 = [&](f32x4 (&aq)[4][2], bf16x8 (&bv)[2][2]) {
    #pragma unroll
    for (int ks = 0; ks < 2; ++ks)
      #pragma unroll
      for (int fr = 0; fr < 4; ++fr)
        #pragma unroll
        for (int fc = 0; fc < 2; ++fc)
          aq[fr][fc] = __builtin_amdgcn_mfma_f32_16x16x32_bf16(
              aF[fr][ks], bv[fc][ks], aq[fr][fc], 0, 0, 0);
  };

  // ---- prologue: 7 half-tiles in flight; wait for tile0's 4 to land ----
  STAGE(0, 0, 0); STAGE(0, 1, 0); STAGE(0, 1, 1); STAGE(0, 0, 1);
  STAGE(1, 0, 0); STAGE(1, 1, 0); STAGE(1, 1, 1);
  WAIT_VM(6);
  BARRIER();

  // ---- main loop: 2 K-tiles / iteration, 8 phases.  NKT=64 -> 31 + peel ----
  #pragma unroll 1
  for (int i = 0; i < 31; ++i) {
    const int t1 = 2 * i + 1, t2 = 2 * i + 2, t3 = 2 * i + 3;
    // ph0: Q0 of tile 2i (buf0)
    LOAD_A(0, 0); LOAD_B(0, 0, bLo); STAGE(t1, 0, 1);
    BARRIER(); WAIT_LGKM0(); PRIO1(); MFMA16(acc[0], bLo); PRIO0(); BARRIER();
    // ph1: Q1
    LOAD_B(0, 1, bHi); STAGE(t2, 0, 0);
    BARRIER(); WAIT_LGKM0(); PRIO1(); MFMA16(acc[1], bHi); PRIO0(); BARRIER();
    // ph2: Q2
    LOAD_A(0, 1); STAGE(t2, 1, 0);
    BARRIER(); WAIT_LGKM0(); PRIO1(); MFMA16(acc[2], bLo); PRIO0(); BARRIER();
    // ph3: Q3 + counted vmcnt (tile 2i+1 complete, 3 half-tiles in flight)
    STAGE(t2, 1, 1);
    BARRIER(); PRIO1(); MFMA16(acc[3], bHi); PRIO0(); WAIT_VM(6); BARRIER();
    // ph4: Q0 of tile 2i+1 (buf1)
    LOAD_A(65536, 0); LOAD_B(65536, 0, bLo); STAGE(t2, 0, 1);
    BARRIER(); WAIT_LGKM0(); PRIO1(); MFMA16(acc[0], bLo); PRIO0(); BARRIER();
    // ph5: Q1
    LOAD_B(65536, 1, bHi); STAGE(t3, 0, 0);
    BARRIER(); WAIT_LGKM0(); PRIO1(); MFMA16(acc[1], bHi); PRIO0(); BARRIER();
    // ph6: Q2
    LOAD_A(65536, 1); STAGE(t3, 1, 0);
    BARRIER(); WAIT_LGKM0(); PRIO1(); MFMA16(acc[2], bLo); PRIO0(); BARRIER();
    // ph7: Q3 + counted vmcnt (tile 2i+2 complete)
    STAGE(t3, 1, 1);
    BARRIER(); PRIO1(); MFMA16(acc[3], bHi); PRIO0(); WAIT_VM(6); BARRIER();
  }
  // ---- peeled last iteration: tiles 62,63; only t63.Ahi left to stage ----
  LOAD_A(0, 0); LOAD_B(0, 0, bLo); STAGE(63, 0, 1);
  BARRIER(); WAIT_LGKM0(); PRIO1(); MFMA16(acc[0], bLo); PRIO0(); BARRIER();
  LOAD_B(0, 1, bHi);
  BARRIER(); WAIT_LGKM0(); PRIO1(); MFMA16(acc[1], bHi); PRIO0(); BARRIER();
  LOAD_A(0, 1);
  BARRIER(); WAIT_LGKM0(); PRIO1(); MFMA16(acc[2], bLo); PRIO0(); BARRIER();
  BARRIER(); PRIO1(); MFMA16(acc[3], bHi); PRIO0(); WAIT_VM(0); BARRIER();
  LOAD_A(65536, 0); LOAD_B(65536, 0, bLo);
  BARRIER(); WAIT_LGKM0(); PRIO1(); MFMA16(acc[0], bLo); PRIO0(); BARRIER();
  LOAD_B(65536, 1, bHi);
  BARRIER(); WAIT_LGKM0(); PRIO1(); MFMA16(acc[1], bHi); PRIO0(); BARRIER();
  LOAD_A(65536, 1);
  BARRIER(); WAIT_LGKM0(); PRIO1(); MFMA16(acc[2], bLo); PRIO0(); BARRIER();
  BARRIER(); WAIT_LGKM0(); PRIO1(); MFMA16(acc[3], bHi); PRIO0();

  // Compiler-only fence: keep epilogue global loads from hoisting above the
  // counted vmcnt waits.
  asm volatile("" ::: "memory");

  // ---- fused epilogue. C/D layout: col = lane&15, row = quad*4 + reg ----
  #pragma unroll
  for (int q = 0; q < 4; ++q) {
    const int rQ = rowBase + wm * 64 + (q >> 1) * 128;
    const int cQ = colBase + wn * 32 + (q & 1) * 128;
    #pragma unroll
    for (int fc = 0; fc < 2; ++fc) {
      const int col = cQ + fc * 16 + lm;
      const float bias = b0[col] + b1[col] + b2[col];
      #pragma unroll
      for (int fr = 0; fr < 4; ++fr) {
        #pragma unroll
        for (int r = 0; r < 4; ++r) {
          const int row = rQ + fr * 16 + quad * 4 + r;
          const size_t idx = (size_t)row * 1024 + col;
          float v = acc[q][fr][fc][r] + bias;
          if constexpr (MODE == MODE_Z) {
            outb[idx] = f2bf(1.f / (1.f + __expf(-v)));
          } else if constexpr (MODE == MODE_R) {
            float rv = 1.f / (1.f + __expf(-v));
            outb[idx] = f2bf(rv * bf2f(hb[idx]));
          } else if constexpr (MODE == MODE_S) {
            float avv = fabsf(v);
            float e = __expf(-2.f * avv);
            float st = (1.f - e) / (1.f + e);      // |tanh|
            st = v < 0.f ? -st : st;
            float zv = bf2f(zb[idx]);
            float hv = bf2f(hb[idx]);
            float s = (1.f - zv) * hv + zv * st;
            outf[idx] = s;
            outb[idx] = f2bf(s);
          } else {  // MODE_T
            outf[idx] = v > 0.f ? v : 0.f;
          }
        }
      }
    }
  }
}

extern "C" void kernel_launch(void* const* d_in, const int* in_sizes, int n_in,
                              void* d_out, int out_size, void* d_ws, size_t ws_size,
                              hipStream_t stream) {
  (void)in_sizes; (void)n_in; (void)out_size; (void)ws_size;
  const float* x  = (const float*)d_in[0];   // [16384,1024]
  const float* h  = (const float*)d_in[1];   // [16384,1024]
  const float* a  = (const float*)d_in[2];   // [16384,2048]
  const float* W   = (const float*)d_in[3];  const float* bw  = (const float*)d_in[4];
  const float* Wz  = (const float*)d_in[5];  const float* bwz = (const float*)d_in[6];
  const float* Wr  = (const float*)d_in[7];  const float* bwr = (const float*)d_in[8];
  const float* U   = (const float*)d_in[9];  const float* bu  = (const float*)d_in[10];
  const float* Uz  = (const float*)d_in[11]; const float* buz = (const float*)d_in[12];
  const float* Ur  = (const float*)d_in[13]; const float* bur = (const float*)d_in[14];
  const float* C   = (const float*)d_in[15]; const float* bc  = (const float*)d_in[16];
  const float* Cz  = (const float*)d_in[17]; const float* bcz = (const float*)d_in[18];
  const float* Cr  = (const float*)d_in[19]; const float* bcr = (const float*)d_in[20];
  const float* Uo  = (const float*)d_in[21]; const float* buo = (const float*)d_in[22];
  const float* Vo  = (const float*)d_in[23]; const float* bvo = (const float*)d_in[24];
  const float* Co  = (const float*)d_in[25]; const float* bco = (const float*)d_in[26];

  const size_t M1 = 1024u * 1024u;           // 1M elements
  unsigned short* wsb = (unsigned short*)d_ws;
  // ws: 12 transposed bf16 weights (32 MB) + x_bf (32 MB) = 64 MB used.
  unsigned short* WzT = wsb + 0 * M1;
  unsigned short* UzT = wsb + 1 * M1;
  unsigned short* WrT = wsb + 2 * M1;
  unsigned short* UrT = wsb + 3 * M1;
  unsigned short* WT  = wsb + 4 * M1;
  unsigned short* UT  = wsb + 5 * M1;
  unsigned short* VoT = wsb + 6 * M1;
  unsigned short* UoT = wsb + 7 * M1;
  unsigned short* CzT = wsb + 8 * M1;        // 2M each from here
  unsigned short* CrT = wsb + 10 * M1;
  unsigned short* CT  = wsb + 12 * M1;
  unsigned short* CoT = wsb + 14 * M1;
  unsigned short* x_bf = wsb + 16 * M1;      // 16M elems

  // Scratch carved out of dead buffers (cross-launch ordering, see header):
  unsigned short* h_bf = (unsigned short*)((float*)d_out + 16 * M1); // d_out t-region
  unsigned short* a_bf = (unsigned short*)d_in[0];                   // x f32 dead after cvt_xh
  unsigned short* rh   = (unsigned short*)d_in[1];                   // h f32 dead after cvt_xh
  unsigned short* z_bf = (unsigned short*)d_in[1] + 16 * M1;
  unsigned short* s_bf = (unsigned short*)d_in[2];                   // a f32 dead after cvt_a

  float* s_out = (float*)d_out;
  float* t_out = (float*)d_out + 16 * M1;

  // 1) convert x,h (must precede a_bf overwriting x's buffer)
  cvt_xh<<<16384, 256, 0, stream>>>(x, h, x_bf, h_bf);
  // 2) convert a into x's (now dead) buffer
  cvt_a<<<16384, 256, 0, stream>>>(a, a_bf);
  // 3) all 12 weight transposes in one launch
  TArgs ta;
  const float* wsrc[12] = {Wz, Uz, Wr, Ur, W, U, Vo, Uo, Cz, Cr, C, Co};
  unsigned short* wdst[12] = {WzT, UzT, WrT, UrT, WT, UT, VoT, UoT, CzT, CrT, CT, CoT};
  for (int i = 0; i < 12; ++i) { ta.src[i] = wsrc[i]; ta.dst[i] = wdst[i]; }
  transpose_all<<<16384, dim3(32, 8), 0, stream>>>(ta);

  dim3 g(256), b(512);
  gemm_fused<MODE_R><<<g, b, 0, stream>>>(x_bf, h_bf, a_bf, WrT, UrT, CrT,
                                          bwr, bur, bcr, h_bf, nullptr, nullptr, rh);
  gemm_fused<MODE_Z><<<g, b, 0, stream>>>(x_bf, h_bf, a_bf, WzT, UzT, CzT,
                                          bwz, buz, bcz, nullptr, nullptr, nullptr, z_bf);
  gemm_fused<MODE_S><<<g, b, 0, stream>>>(x_bf, rh, a_bf, WT, UT, CT,
                                          bw, bu, bc, h_bf, z_bf, s_out, s_bf);
  gemm_fused<MODE_T><<<g, b, 0, stream>>>(x_bf, s_bf, a_bf, VoT, UoT, CoT,
                                          bvo, buo, bco, nullptr, nullptr, t_out, nullptr);
}